// Round 11
// baseline (716.590 us; speedup 1.0000x reference)
//
#include <hip/hip_runtime.h>
#include <math.h>

#define NPTS 262144
#define MT 64          // points per block
#define XS 264         // LDS activation row stride (bf16): 256 + 8 pad

typedef __attribute__((ext_vector_type(8))) short bf16x8;
typedef __attribute__((ext_vector_type(4))) float f32x4;
typedef __attribute__((ext_vector_type(2))) unsigned int u32x2;

#if defined(__has_builtin)
#if __has_builtin(__builtin_amdgcn_cvt_pk_bf16_f32)
#define HAVE_CVT_PK_BF16 1
#endif
#endif

__device__ __forceinline__ short f2bf(float f) {
    union { float f; unsigned u; } v; v.f = f;
    unsigned r = v.u + 0x7fffu + ((v.u >> 16) & 1u);   // RNE
    return (short)(r >> 16);
}
__device__ __forceinline__ unsigned pk2(float a, float b) {
#ifdef HAVE_CVT_PK_BF16
    auto r = __builtin_amdgcn_cvt_pk_bf16_f32(a, b);   // 1 instr, RNE
    unsigned u; __builtin_memcpy(&u, &r, 4);
    return u;
#else
    return ((unsigned)(unsigned short)f2bf(a)) |
           ((unsigned)(unsigned short)f2bf(b) << 16);
#endif
}

// pe B-fragment on the fly (bit-identical to a precomputed-LDS path)
__device__ __forceinline__ bf16x8 pe_frag(float x0, float x1, float x2, int base) {
    float vv[8];
#pragma unroll
    for (int j = 0; j < 8; j++) {
        const int d = base + j;
        float v = 0.f;
        if (d < 3) v = (d == 0) ? x0 : ((d == 1) ? x1 : x2);
        else if (d < 63) {
            const int e = d - 3, f = e / 6, r = e % 6;
            const int c = (r < 3) ? r : r - 3;
            const float x = (c == 0) ? x0 : ((c == 1) ? x1 : x2);
            const float xf = x * (float)(1 << f);
            v = (r < 3) ? sinf(xf) : cosf(xf);
        }
        vv[j] = v;
    }
    union { unsigned u4[4]; bf16x8 b; } cv;
    cv.u4[0] = pk2(vv[0], vv[1]); cv.u4[1] = pk2(vv[2], vv[3]);
    cv.u4[2] = pk2(vv[4], vv[5]); cv.u4[3] = pk2(vv[6], vv[7]);
    return cv.b;
}

// ---- swizzled-weight workspace layout (offsets in bf16 elements) ----
#define OFF_IN   0
#define SZ_IN    (64*256)
#define OFF_H0   (OFF_IN + SZ_IN)
#define SZ_H     (256*256)
#define OFF_H1   (OFF_H0 + SZ_H)
#define OFF_H2   (OFF_H1 + SZ_H)
#define OFF_H3   (OFF_H2 + SZ_H)
#define OFF_H4   (OFF_H3 + SZ_H)
#define SZ_H4    (320*256)
#define OFF_H5   (OFF_H4 + SZ_H4)
#define OFF_H6   (OFF_H5 + SZ_H)
#define OFF_OUT  (OFF_H6 + SZ_H)
#define SZ_OUT   (256*272)          // N padded to 272 = 17 tiles (density tile = 16)
#define OFF_R1   (OFF_OUT + SZ_OUT)
#define SZ_R1    (288*128)
#define OFF_R2   (OFF_R1 + SZ_R1)
#define SZ_R2    (128*16)
#define WS_TOTAL (OFF_R2 + SZ_R2)

// ---------------- weight prep: f32 -> bf16, 16x16x32 fragment swizzle -------
struct PrepP { const float* W[11]; short* ws; };

__global__ __launch_bounds__(256) void prep_all(PrepP pp) {
    int i = blockIdx.x * 256 + threadIdx.x;
    if (i >= WS_TOTAL) return;
    const int offs[12] = {OFF_IN, OFF_H0, OFF_H1, OFF_H2, OFF_H3, OFF_H4,
                          OFF_H5, OFF_H6, OFF_OUT, OFF_R1, OFF_R2, WS_TOTAL};
    const int Ks[11]  = {63,256,256,256,256,319,256,256,256,283,128};
    const int Ns[11]  = {256,256,256,256,256,256,256,256,257,128,3};
    const int Nps[11] = {256,256,256,256,256,256,256,256,272,128,16};
    int seg = 0;
    while (i >= offs[seg + 1]) seg++;
    int li = i - offs[seg];
    int j = li & 7, L = (li >> 3) & 63, tile = li >> 9;
    int nNt = Nps[seg] >> 4;
    int nt = tile % nNt, kt = tile / nNt;
    int k = kt * 32 + ((L >> 4) << 3) + j;
    int n = nt * 16 + (L & 15);
    float v = (k < Ks[seg] && n < Ns[seg]) ? pp.W[seg][k * Ns[seg] + n] : 0.f;
    pp.ws[i] = f2bf(v);
}

// ---------------- fused MLP ----------------
struct Params {
    const float *pos, *dir;
    const float *b_in, *b_h0, *b_h1, *b_h2, *b_h3, *b_h4, *b_h5, *b_h6;
    const float *b_out, *b_r1, *b_r2;
    const short *w;
    float *out;
};

// Ping-pong layer: reads Xin, writes Xout (!= Xin) -> ONE barrier per layer.
// Entry __syncthreads makes the previous layer's Xin writes visible; Xin is
// not overwritten until two barriers later, so no exit barrier is needed.
// Transposed MFMA: A = W^T (rows = feature n), B = Xin^T (cols = point m).
// 8 waves/block, NS=2 n-tiles x TM=4 m-tiles; NO in-wave prefetch (R6-style
// loop): acc 32 + b[4] 16 + transient a + addr ~= 116 unified regs -> fits the
// (512,4) 128-reg cap -> 16 waves/CU (latency hiding via TLP, not prefetch).
// PEKT trailing k-tiles: B computed on the fly from pos.  DEKT: B from DE.
// MODE 1: out layer; density row (tile 16, n==256) via waves 0..3 pre-pass.
template<int NKT, int NT, int NS, int TM, int MODE, int PEKT, int DEKT>
__device__ __forceinline__ void layerP(const short* __restrict__ Wsw,
                                       const float* __restrict__ bias,
                                       const short* Xin, short* Xout,
                                       const short* DE,
                                       const float* __restrict__ pos,
                                       float* dout, int p0,
                                       int ntB, int wave, int lane) {
    const int l15 = lane & 15, quad = lane >> 4;
    constexpr int NKTL = NKT - PEKT - DEKT;
    const short* xb = Xin + l15 * XS + quad * 8;
    const short* wp = Wsw + (size_t)(ntB * 64 + lane) * 8;   // + kt*NT*512 + s*512

    // pos preload for on-the-fly pe (independent of Xin -> before the barrier)
    float px[TM], py[TM], pz[TM];
    if (PEKT > 0) {
#pragma unroll
        for (int t = 0; t < TM; t++) {
            const int pt = p0 + t * 16 + l15;
            px[t] = pos[pt * 3 + 0];
            py[t] = pos[pt * 3 + 1];
            pz[t] = pos[pt * 3 + 2];
        }
    }

    __syncthreads();                      // Xin (this layer's input) is ready

    if (MODE == 1 && wave < 4) {          // density pre-pass: m-tile = wave
        f32x4 ad = (f32x4){0.f, 0.f, 0.f, 0.f};
        for (int kt = 0; kt < NKT; ++kt) {
            bf16x8 b = *(const bf16x8*)(xb + wave * 16 * XS + kt * 32);
            bf16x8 a = *(const bf16x8*)(Wsw + (size_t)((kt * NT + 16) * 64 + lane) * 8);
            ad = __builtin_amdgcn_mfma_f32_16x16x32_bf16(a, b, ad, 0, 0, 0);
        }
        if (quad == 0)                    // C row 0 = n 256 (density)
            dout[3 * NPTS + p0 + wave * 16 + l15] = fmaxf(ad[0] + bias[256], 0.f);
    }

    f32x4 acc[NS][TM];
#pragma unroll
    for (int s = 0; s < NS; s++)
#pragma unroll
        for (int t = 0; t < TM; t++) acc[s][t] = (f32x4){0.f, 0.f, 0.f, 0.f};

    for (int kt = 0; kt < NKTL; ++kt) {   // ---- main K-loop (no prefetch) ----
        bf16x8 b[TM];
#pragma unroll
        for (int t = 0; t < TM; t++)
            b[t] = *(const bf16x8*)(xb + t * 16 * XS + kt * 32);
#pragma unroll
        for (int s = 0; s < NS; s++) {
            bf16x8 a = *(const bf16x8*)(wp + (size_t)kt * NT * 512 + (size_t)s * 512);
#pragma unroll
            for (int t = 0; t < TM; t++)
                acc[s][t] = __builtin_amdgcn_mfma_f32_16x16x32_bf16(a, b[t], acc[s][t], 0, 0, 0);
        }
    }

#pragma unroll
    for (int w = 0; w < PEKT; w++) {      // ---- pe tail (computed B) ----
        const int kt = NKTL + w;
#pragma unroll
        for (int t = 0; t < TM; t++) {
            bf16x8 b = pe_frag(px[t], py[t], pz[t], w * 32 + quad * 8);
#pragma unroll
            for (int s = 0; s < NS; s++) {
                bf16x8 a = *(const bf16x8*)(wp + (size_t)kt * NT * 512 + (size_t)s * 512);
                acc[s][t] = __builtin_amdgcn_mfma_f32_16x16x32_bf16(a, b, acc[s][t], 0, 0, 0);
            }
        }
    }

    if (DEKT > 0) {                       // ---- de tail (B from DE buffer) ----
        const int kt = NKT - 1;
#pragma unroll
        for (int t = 0; t < TM; t++) {
            bf16x8 b = *(const bf16x8*)(DE + (t * 16 + l15) * 32 + quad * 8);
#pragma unroll
            for (int s = 0; s < NS; s++) {
                bf16x8 a = *(const bf16x8*)(wp + (size_t)kt * NT * 512 + (size_t)s * 512);
                acc[s][t] = __builtin_amdgcn_mfma_f32_16x16x32_bf16(a, b, acc[s][t], 0, 0, 0);
            }
        }
    }

    // ---- epilogue straight to Xout (no exit barrier: Xout != Xin) ----
#pragma unroll
    for (int s = 0; s < NS; s++) {
        const int n0 = (ntB + s) * 16 + quad * 4;
        const f32x4 bv = *(const f32x4*)(bias + n0);
#pragma unroll
        for (int t = 0; t < TM; t++) {
            const int m = t * 16 + l15;
            float v0 = acc[s][t][0] + bv[0];
            float v1 = acc[s][t][1] + bv[1];
            float v2 = acc[s][t][2] + bv[2];
            float v3 = acc[s][t][3] + bv[3];
            if (MODE == 0) {
                v0 = fmaxf(v0, 0.f); v1 = fmaxf(v1, 0.f);
                v2 = fmaxf(v2, 0.f); v3 = fmaxf(v3, 0.f);
            }
            u32x2 w; w[0] = pk2(v0, v1); w[1] = pk2(v2, v3);
            *(u32x2*)(Xout + m * XS + n0) = w;
        }
    }
}

__global__ __launch_bounds__(512, 4) void nerf_fused(Params P) {
    extern __shared__ short smem[];
    short* X0 = smem;                      // MT x XS
    short* X1 = smem + MT * XS;            // MT x XS
    short* DE = smem + 2 * MT * XS;        // MT x 32   -> 71680 B total
    const int tid = threadIdx.x;
    const int wave = tid >> 6, lane = tid & 63;
    const int p0 = blockIdx.x * MT;

    // hidden/out layers: NS=2 n-tiles x TM=4 m-tiles per wave (8 waves -> 16 nt)
    const int ntB_h = wave * 2;
    // r1 (8 n-tiles): NS=1
    const int ntB_r = wave;

    // ---- directional encoding -> DE buffer (pe is computed on the fly) ----
    for (int i = tid; i < MT * 32; i += 512) {
        const int pt = i >> 5, d = i & 31;
        float v = 0.f;
        if (d < 3) v = P.dir[(p0 + pt) * 3 + d];
        else if (d < 27) {
            const int e = d - 3, f = e / 6, r = e % 6;
            const float x = P.dir[(p0 + pt) * 3 + (r % 3)];
            const float xf = x * (float)(1 << f);
            v = (r < 3) ? sinf(xf) : cosf(xf);
        }
        DE[i] = f2bf(v);
    }

    // ping-pong chain (Xin, Xout); input layer reads nothing (NKTL=0)
    layerP<2, 16, 2, 4, 0, 2, 0>(P.w + OFF_IN, P.b_in, X1, X0, DE, P.pos, P.out, p0, ntB_h, wave, lane);
    layerP<8, 16, 2, 4, 0, 0, 0>(P.w + OFF_H0, P.b_h0, X0, X1, DE, P.pos, P.out, p0, ntB_h, wave, lane);
    layerP<8, 16, 2, 4, 0, 0, 0>(P.w + OFF_H1, P.b_h1, X1, X0, DE, P.pos, P.out, p0, ntB_h, wave, lane);
    layerP<8, 16, 2, 4, 0, 0, 0>(P.w + OFF_H2, P.b_h2, X0, X1, DE, P.pos, P.out, p0, ntB_h, wave, lane);
    layerP<8, 16, 2, 4, 0, 0, 0>(P.w + OFF_H3, P.b_h3, X1, X0, DE, P.pos, P.out, p0, ntB_h, wave, lane);
    layerP<10, 16, 2, 4, 0, 2, 0>(P.w + OFF_H4, P.b_h4, X0, X1, DE, P.pos, P.out, p0, ntB_h, wave, lane); // concat(h,pe)
    layerP<8, 16, 2, 4, 0, 0, 0>(P.w + OFF_H5, P.b_h5, X1, X0, DE, P.pos, P.out, p0, ntB_h, wave, lane);
    layerP<8, 16, 2, 4, 0, 0, 0>(P.w + OFF_H6, P.b_h6, X0, X1, DE, P.pos, P.out, p0, ntB_h, wave, lane);
    layerP<8, 17, 2, 4, 1, 0, 0>(P.w + OFF_OUT, P.b_out, X1, X0, DE, P.pos, P.out, p0, ntB_h, wave, lane);
    layerP<9, 8, 1, 4, 0, 0, 1>(P.w + OFF_R1, P.b_r1, X0, X1, DE, P.pos, P.out, p0, ntB_r, wave, lane);

    // ---- r2 (128 -> 3) + sigmoid; waves 0..3 each take one 16-point tile ----
    __syncthreads();
    if (wave < 4) {
        const int l15 = lane & 15, quad = lane >> 4;
        f32x4 acc = (f32x4){0.f, 0.f, 0.f, 0.f};
        const short* xb = X1 + (wave * 16 + l15) * XS + quad * 8;
#pragma unroll
        for (int kt = 0; kt < 4; ++kt) {
            bf16x8 b = *(const bf16x8*)(xb + kt * 32);
            bf16x8 a = *(const bf16x8*)(P.w + OFF_R2 + (size_t)(kt * 64 + lane) * 8);
            acc = __builtin_amdgcn_mfma_f32_16x16x32_bf16(a, b, acc, 0, 0, 0);
        }
        if (quad == 0) {                   // rows r = rgb channel
#pragma unroll
            for (int r = 0; r < 3; r++) {
                const float v = acc[r] + P.b_r2[r];
                P.out[(size_t)(p0 + wave * 16 + l15) * 3 + r] = 1.f / (1.f + expf(-v));
            }
        }
    }
}

#define SMEM_BYTES ((2 * MT * XS + MT * 32) * 2)   // 71680 B -> 2 blocks/CU

extern "C" void kernel_launch(void* const* d_in, const int* in_sizes, int n_in,
                              void* d_out, int out_size, void* d_ws, size_t ws_size,
                              hipStream_t stream) {
    short* ws = (short*)d_ws;

    PrepP pp;
    pp.W[0]  = (const float*)d_in[2];   // W_in
    pp.W[1]  = (const float*)d_in[4];   // W_h0
    pp.W[2]  = (const float*)d_in[6];   // W_h1
    pp.W[3]  = (const float*)d_in[8];   // W_h2
    pp.W[4]  = (const float*)d_in[10];  // W_h3
    pp.W[5]  = (const float*)d_in[12];  // W_h4
    pp.W[6]  = (const float*)d_in[14];  // W_h5
    pp.W[7]  = (const float*)d_in[16];  // W_h6
    pp.W[8]  = (const float*)d_in[18];  // W_out
    pp.W[9]  = (const float*)d_in[20];  // W_r1
    pp.W[10] = (const float*)d_in[22];  // W_r2
    pp.ws = ws;
    hipLaunchKernelGGL(prep_all, dim3((WS_TOTAL + 255) / 256), dim3(256), 0, stream, pp);

    Params P;
    P.pos  = (const float*)d_in[0];
    P.dir  = (const float*)d_in[1];
    P.b_in = (const float*)d_in[3];
    P.b_h0 = (const float*)d_in[5];
    P.b_h1 = (const float*)d_in[7];
    P.b_h2 = (const float*)d_in[9];
    P.b_h3 = (const float*)d_in[11];
    P.b_h4 = (const float*)d_in[13];
    P.b_h5 = (const float*)d_in[15];
    P.b_h6 = (const float*)d_in[17];
    P.b_out = (const float*)d_in[19];
    P.b_r1 = (const float*)d_in[21];
    P.b_r2 = (const float*)d_in[23];
    P.w = ws;
    P.out = (float*)d_out;

    (void)hipFuncSetAttribute((const void*)nerf_fused,
                              hipFuncAttributeMaxDynamicSharedMemorySize, SMEM_BYTES);
    hipLaunchKernelGGL(nerf_fused, dim3(NPTS / MT), dim3(512), SMEM_BYTES, stream, P);
}

// Round 12
// 451.344 us; speedup vs baseline: 1.5877x; 1.5877x over previous
//
#include <hip/hip_runtime.h>
#include <math.h>

#define NPTS 262144
#define MT 64          // points per block
#define XS 264         // LDS activation row stride (bf16): 256 + 8 pad
#define PES 72         // PE buffer row stride (64 + 8 pad)

typedef __attribute__((ext_vector_type(8))) short bf16x8;
typedef __attribute__((ext_vector_type(4))) float f32x4;
typedef __attribute__((ext_vector_type(2))) unsigned int u32x2;

#if defined(__has_builtin)
#if __has_builtin(__builtin_amdgcn_cvt_pk_bf16_f32)
#define HAVE_CVT_PK_BF16 1
#endif
#endif

__device__ __forceinline__ short f2bf(float f) {
    union { float f; unsigned u; } v; v.f = f;
    unsigned r = v.u + 0x7fffu + ((v.u >> 16) & 1u);   // RNE
    return (short)(r >> 16);
}
__device__ __forceinline__ unsigned pk2(float a, float b) {
#ifdef HAVE_CVT_PK_BF16
    auto r = __builtin_amdgcn_cvt_pk_bf16_f32(a, b);   // 1 instr, RNE
    unsigned u; __builtin_memcpy(&u, &r, 4);
    return u;
#else
    return ((unsigned)(unsigned short)f2bf(a)) |
           ((unsigned)(unsigned short)f2bf(b) << 16);
#endif
}

// ---- swizzled-weight workspace layout (offsets in bf16 elements) ----
#define OFF_IN   0
#define SZ_IN    (64*256)
#define OFF_H0   (OFF_IN + SZ_IN)
#define SZ_H     (256*256)
#define OFF_H1   (OFF_H0 + SZ_H)
#define OFF_H2   (OFF_H1 + SZ_H)
#define OFF_H3   (OFF_H2 + SZ_H)
#define OFF_H4   (OFF_H3 + SZ_H)
#define SZ_H4    (320*256)
#define OFF_H5   (OFF_H4 + SZ_H4)
#define OFF_H6   (OFF_H5 + SZ_H)
#define OFF_OUT  (OFF_H6 + SZ_H)
#define SZ_OUT   (256*272)          // N padded to 272 = 17 tiles (density tile = 16)
#define OFF_R1   (OFF_OUT + SZ_OUT)
#define SZ_R1    (288*128)
#define OFF_R2   (OFF_R1 + SZ_R1)
#define SZ_R2    (128*16)
#define WS_TOTAL (OFF_R2 + SZ_R2)

// ---------------- weight prep: f32 -> bf16, 16x16x32 fragment swizzle -------
struct PrepP { const float* W[11]; short* ws; };

__global__ __launch_bounds__(256) void prep_all(PrepP pp) {
    int i = blockIdx.x * 256 + threadIdx.x;
    if (i >= WS_TOTAL) return;
    const int offs[12] = {OFF_IN, OFF_H0, OFF_H1, OFF_H2, OFF_H3, OFF_H4,
                          OFF_H5, OFF_H6, OFF_OUT, OFF_R1, OFF_R2, WS_TOTAL};
    const int Ks[11]  = {63,256,256,256,256,319,256,256,256,283,128};
    const int Ns[11]  = {256,256,256,256,256,256,256,256,257,128,3};
    const int Nps[11] = {256,256,256,256,256,256,256,256,272,128,16};
    int seg = 0;
    while (i >= offs[seg + 1]) seg++;
    int li = i - offs[seg];
    int j = li & 7, L = (li >> 3) & 63, tile = li >> 9;
    int nNt = Nps[seg] >> 4;
    int nt = tile % nNt, kt = tile / nNt;
    int k = kt * 32 + ((L >> 4) << 3) + j;
    int n = nt * 16 + (L & 15);
    float v = (k < Ks[seg] && n < Ns[seg]) ? pp.W[seg][k * Ns[seg] + n] : 0.f;
    pp.ws[i] = f2bf(v);
}

// ---------------- fused MLP ----------------
struct Params {
    const float *pos, *dir;
    const float *b_in, *b_h0, *b_h1, *b_h2, *b_h3, *b_h4, *b_h5, *b_h6;
    const float *b_out, *b_r1, *b_r2;
    const short *w;
    float *out;
};

// Ping-pong layer: reads Xin, writes Xout (!= Xin) -> ONE barrier per layer.
// Transposed MFMA: A = W^T (rows = feature n), B = Xin^T (cols = point m).
// 8 waves/block, NS=2 n-tiles x TM=4 m-tiles, no in-wave prefetch: ~90-110
// unified regs -> fits the (512,4) 128-reg cap -> 16 waves/CU.
// PEKT trailing k-tiles: B-frags from the precomputed PE LDS buffer (pe is
// computed ONCE per block -- R11 showed on-the-fly pe saturates VALU at 91%).
// DEKT trailing k-tile: B from the DE buffer.
// MODE 1: out layer; density row (tile 16, n==256) via waves 0..3 pre-pass.
template<int NKT, int NT, int NS, int TM, int MODE, int PEKT, int DEKT>
__device__ __forceinline__ void layerP(const short* __restrict__ Wsw,
                                       const float* __restrict__ bias,
                                       const short* Xin, short* Xout,
                                       const short* PE, const short* DE,
                                       float* dout, int p0,
                                       int ntB, int wave, int lane) {
    const int l15 = lane & 15, quad = lane >> 4;
    constexpr int NKTL = NKT - PEKT - DEKT;
    const short* xb = Xin + l15 * XS + quad * 8;
    const short* wp = Wsw + (size_t)(ntB * 64 + lane) * 8;   // + kt*NT*512 + s*512

    __syncthreads();                      // Xin (this layer's input) is ready

    if (MODE == 1 && wave < 4) {          // density pre-pass: m-tile = wave
        f32x4 ad = (f32x4){0.f, 0.f, 0.f, 0.f};
        for (int kt = 0; kt < NKT; ++kt) {
            bf16x8 b = *(const bf16x8*)(xb + wave * 16 * XS + kt * 32);
            bf16x8 a = *(const bf16x8*)(Wsw + (size_t)((kt * NT + 16) * 64 + lane) * 8);
            ad = __builtin_amdgcn_mfma_f32_16x16x32_bf16(a, b, ad, 0, 0, 0);
        }
        if (quad == 0)                    // C row 0 = n 256 (density)
            dout[3 * NPTS + p0 + wave * 16 + l15] = fmaxf(ad[0] + bias[256], 0.f);
    }

    f32x4 acc[NS][TM];
#pragma unroll
    for (int s = 0; s < NS; s++)
#pragma unroll
        for (int t = 0; t < TM; t++) acc[s][t] = (f32x4){0.f, 0.f, 0.f, 0.f};

    for (int kt = 0; kt < NKTL; ++kt) {   // ---- main K-loop (no prefetch) ----
        bf16x8 b[TM];
#pragma unroll
        for (int t = 0; t < TM; t++)
            b[t] = *(const bf16x8*)(xb + t * 16 * XS + kt * 32);
#pragma unroll
        for (int s = 0; s < NS; s++) {
            bf16x8 a = *(const bf16x8*)(wp + (size_t)kt * NT * 512 + (size_t)s * 512);
#pragma unroll
            for (int t = 0; t < TM; t++)
                acc[s][t] = __builtin_amdgcn_mfma_f32_16x16x32_bf16(a, b[t], acc[s][t], 0, 0, 0);
        }
    }

#pragma unroll
    for (int w = 0; w < PEKT; w++) {      // ---- pe tail (B from PE buffer) ----
        const int kt = NKTL + w;
#pragma unroll
        for (int t = 0; t < TM; t++) {
            bf16x8 b = *(const bf16x8*)(PE + (t * 16 + l15) * PES + w * 32 + quad * 8);
#pragma unroll
            for (int s = 0; s < NS; s++) {
                bf16x8 a = *(const bf16x8*)(wp + (size_t)kt * NT * 512 + (size_t)s * 512);
                acc[s][t] = __builtin_amdgcn_mfma_f32_16x16x32_bf16(a, b, acc[s][t], 0, 0, 0);
            }
        }
    }

    if (DEKT > 0) {                       // ---- de tail (B from DE buffer) ----
        const int kt = NKT - 1;
#pragma unroll
        for (int t = 0; t < TM; t++) {
            bf16x8 b = *(const bf16x8*)(DE + (t * 16 + l15) * 32 + quad * 8);
#pragma unroll
            for (int s = 0; s < NS; s++) {
                bf16x8 a = *(const bf16x8*)(wp + (size_t)kt * NT * 512 + (size_t)s * 512);
                acc[s][t] = __builtin_amdgcn_mfma_f32_16x16x32_bf16(a, b, acc[s][t], 0, 0, 0);
            }
        }
    }

    // ---- epilogue straight to Xout (no exit barrier: Xout != Xin) ----
#pragma unroll
    for (int s = 0; s < NS; s++) {
        const int n0 = (ntB + s) * 16 + quad * 4;
        const f32x4 bv = *(const f32x4*)(bias + n0);
#pragma unroll
        for (int t = 0; t < TM; t++) {
            const int m = t * 16 + l15;
            float v0 = acc[s][t][0] + bv[0];
            float v1 = acc[s][t][1] + bv[1];
            float v2 = acc[s][t][2] + bv[2];
            float v3 = acc[s][t][3] + bv[3];
            if (MODE == 0) {
                v0 = fmaxf(v0, 0.f); v1 = fmaxf(v1, 0.f);
                v2 = fmaxf(v2, 0.f); v3 = fmaxf(v3, 0.f);
            }
            u32x2 w; w[0] = pk2(v0, v1); w[1] = pk2(v2, v3);
            *(u32x2*)(Xout + m * XS + n0) = w;
        }
    }
}

__global__ __launch_bounds__(512, 4) void nerf_fused(Params P) {
    extern __shared__ short smem[];
    short* X0 = smem;                      // MT x XS   (33792 B)
    short* X1 = smem + MT * XS;            // MT x XS   (33792 B)
    short* PE = smem + 2 * MT * XS;        // MT x PES  ( 9216 B)
    short* DE = PE + MT * PES;             // MT x 32   ( 4096 B) -> 80896 total
    const int tid = threadIdx.x;
    const int wave = tid >> 6, lane = tid & 63;
    const int p0 = blockIdx.x * MT;

    // hidden/out layers: NS=2 n-tiles x TM=4 m-tiles per wave (8 waves -> 16 nt)
    const int ntB_h = wave * 2;
    // r1 (8 n-tiles): NS=1
    const int ntB_r = wave;

    // ---- positional encoding -> PE buffer (once per block) ----
    for (int i = tid; i < MT * 64; i += 512) {
        const int pt = i >> 6, d = i & 63;
        float v = 0.f;
        if (d < 3) v = P.pos[(p0 + pt) * 3 + d];
        else if (d < 63) {
            const int e = d - 3, f = e / 6, r = e % 6;
            const float x = P.pos[(p0 + pt) * 3 + (r % 3)];
            const float xf = x * (float)(1 << f);
            v = (r < 3) ? sinf(xf) : cosf(xf);
        }
        PE[pt * PES + d] = f2bf(v);
    }
    // ---- directional encoding -> DE buffer ----
    for (int i = tid; i < MT * 32; i += 512) {
        const int pt = i >> 5, d = i & 31;
        float v = 0.f;
        if (d < 3) v = P.dir[(p0 + pt) * 3 + d];
        else if (d < 27) {
            const int e = d - 3, f = e / 6, r = e % 6;
            const float x = P.dir[(p0 + pt) * 3 + (r % 3)];
            const float xf = x * (float)(1 << f);
            v = (r < 3) ? sinf(xf) : cosf(xf);
        }
        DE[i] = f2bf(v);
    }

    // ping-pong chain (Xin, Xout); input layer reads only PE (NKTL=0)
    layerP<2, 16, 2, 4, 0, 2, 0>(P.w + OFF_IN, P.b_in, X1, X0, PE, DE, P.out, p0, ntB_h, wave, lane);
    layerP<8, 16, 2, 4, 0, 0, 0>(P.w + OFF_H0, P.b_h0, X0, X1, PE, DE, P.out, p0, ntB_h, wave, lane);
    layerP<8, 16, 2, 4, 0, 0, 0>(P.w + OFF_H1, P.b_h1, X1, X0, PE, DE, P.out, p0, ntB_h, wave, lane);
    layerP<8, 16, 2, 4, 0, 0, 0>(P.w + OFF_H2, P.b_h2, X0, X1, PE, DE, P.out, p0, ntB_h, wave, lane);
    layerP<8, 16, 2, 4, 0, 0, 0>(P.w + OFF_H3, P.b_h3, X1, X0, PE, DE, P.out, p0, ntB_h, wave, lane);
    layerP<10, 16, 2, 4, 0, 2, 0>(P.w + OFF_H4, P.b_h4, X0, X1, PE, DE, P.out, p0, ntB_h, wave, lane); // concat(h,pe)
    layerP<8, 16, 2, 4, 0, 0, 0>(P.w + OFF_H5, P.b_h5, X1, X0, PE, DE, P.out, p0, ntB_h, wave, lane);
    layerP<8, 16, 2, 4, 0, 0, 0>(P.w + OFF_H6, P.b_h6, X0, X1, PE, DE, P.out, p0, ntB_h, wave, lane);
    layerP<8, 17, 2, 4, 1, 0, 0>(P.w + OFF_OUT, P.b_out, X1, X0, PE, DE, P.out, p0, ntB_h, wave, lane);
    layerP<9, 8, 1, 4, 0, 0, 1>(P.w + OFF_R1, P.b_r1, X0, X1, PE, DE, P.out, p0, ntB_r, wave, lane);

    // ---- r2 (128 -> 3) + sigmoid; waves 0..3 each take one 16-point tile ----
    __syncthreads();
    if (wave < 4) {
        const int l15 = lane & 15, quad = lane >> 4;
        f32x4 acc = (f32x4){0.f, 0.f, 0.f, 0.f};
        const short* xb = X1 + (wave * 16 + l15) * XS + quad * 8;
#pragma unroll
        for (int kt = 0; kt < 4; ++kt) {
            bf16x8 b = *(const bf16x8*)(xb + kt * 32);
            bf16x8 a = *(const bf16x8*)(P.w + OFF_R2 + (size_t)(kt * 64 + lane) * 8);
            acc = __builtin_amdgcn_mfma_f32_16x16x32_bf16(a, b, acc, 0, 0, 0);
        }
        if (quad == 0) {                   // rows r = rgb channel
#pragma unroll
            for (int r = 0; r < 3; r++) {
                const float v = acc[r] + P.b_r2[r];
                P.out[(size_t)(p0 + wave * 16 + l15) * 3 + r] = 1.f / (1.f + expf(-v));
            }
        }
    }
}

#define SMEM_BYTES ((2 * MT * XS + MT * PES + MT * 32) * 2)   // 80896 B -> 2 blocks/CU

extern "C" void kernel_launch(void* const* d_in, const int* in_sizes, int n_in,
                              void* d_out, int out_size, void* d_ws, size_t ws_size,
                              hipStream_t stream) {
    short* ws = (short*)d_ws;

    PrepP pp;
    pp.W[0]  = (const float*)d_in[2];   // W_in
    pp.W[1]  = (const float*)d_in[4];   // W_h0
    pp.W[2]  = (const float*)d_in[6];   // W_h1
    pp.W[3]  = (const float*)d_in[8];   // W_h2
    pp.W[4]  = (const float*)d_in[10];  // W_h3
    pp.W[5]  = (const float*)d_in[12];  // W_h4
    pp.W[6]  = (const float*)d_in[14];  // W_h5
    pp.W[7]  = (const float*)d_in[16];  // W_h6
    pp.W[8]  = (const float*)d_in[18];  // W_out
    pp.W[9]  = (const float*)d_in[20];  // W_r1
    pp.W[10] = (const float*)d_in[22];  // W_r2
    pp.ws = ws;
    hipLaunchKernelGGL(prep_all, dim3((WS_TOTAL + 255) / 256), dim3(256), 0, stream, pp);

    Params P;
    P.pos  = (const float*)d_in[0];
    P.dir  = (const float*)d_in[1];
    P.b_in = (const float*)d_in[3];
    P.b_h0 = (const float*)d_in[5];
    P.b_h1 = (const float*)d_in[7];
    P.b_h2 = (const float*)d_in[9];
    P.b_h3 = (const float*)d_in[11];
    P.b_h4 = (const float*)d_in[13];
    P.b_h5 = (const float*)d_in[15];
    P.b_h6 = (const float*)d_in[17];
    P.b_out = (const float*)d_in[19];
    P.b_r1 = (const float*)d_in[21];
    P.b_r2 = (const float*)d_in[23];
    P.w = ws;
    P.out = (float*)d_out;

    (void)hipFuncSetAttribute((const void*)nerf_fused,
                              hipFuncAttributeMaxDynamicSharedMemorySize, SMEM_BYTES);
    hipLaunchKernelGGL(nerf_fused, dim3(NPTS / MT), dim3(512), SMEM_BYTES, stream, P);
}